// Round 1
// baseline (92.617 us; speedup 1.0000x reference)
//
#include <hip/hip_runtime.h>
#include <hip/hip_bf16.h>

// Problem: N=8192, D=512, H=4, QK=128
// Reference reduces algebraically:
//   softmax rows sum to 1  =>  attn.mean(heads).mean(keys) == 1/N exactly
//   b_q[n]    = sigmoid(r[n]) / (sum_m sigmoid(r[m]) + N*1e-8)
//   attended  = (patch * b_q[:,None]) @ Wout^T
// Output: attended (N*D floats) then b_q (N floats), fp32.

#define NPTS 8192
#define DDIM 512

#define BM 64
#define BN 64
#define BK 64
#define LDS_PAD 8          // +8 bf16 per row: row stride 144B -> 2-way LDS bank alias (free)
#define LDK (BK + LDS_PAD) // 72

typedef __attribute__((ext_vector_type(8))) short bf16x8;   // 8 bf16 in 4 VGPRs
typedef __attribute__((ext_vector_type(4))) float f32x4;    // MFMA accumulator
typedef __attribute__((ext_vector_type(8))) unsigned short us8;

static __device__ __forceinline__ unsigned short f2bf(float f) {
    // round-to-nearest-even fp32 -> bf16 (inputs are finite gaussians; no NaN handling)
    unsigned int u = __float_as_uint(f);
    u += 0x7fffu + ((u >> 16) & 1u);
    return (unsigned short)(u >> 16);
}

// ---------------------------------------------------------------------------
// Kernel 1: b_q = sigmoid(r) / (sum(sigmoid(r)) + N*1e-8), written to out tail
// ---------------------------------------------------------------------------
__global__ __launch_bounds__(1024) void bq_kernel(const float* __restrict__ r,
                                                  float* __restrict__ out_tail) {
    const int t = threadIdx.x;           // 1024 threads, 1 block
    float sv[8];
    float local = 0.0f;
#pragma unroll
    for (int k = 0; k < 8; ++k) {
        float x = r[t + 1024 * k];
        float s = 1.0f / (1.0f + expf(-x));
        sv[k] = s;
        local += s;
    }
    // wave-64 reduction
#pragma unroll
    for (int off = 32; off >= 1; off >>= 1)
        local += __shfl_down(local, off, 64);

    __shared__ float wsum[16];
    __shared__ float stot;
    if ((t & 63) == 0) wsum[t >> 6] = local;
    __syncthreads();
    if (t == 0) {
        float tot = 0.0f;
#pragma unroll
        for (int i = 0; i < 16; ++i) tot += wsum[i];
        stot = tot;
    }
    __syncthreads();
    const float inv = 1.0f / (stot + (float)NPTS * 1e-8f);
#pragma unroll
    for (int k = 0; k < 8; ++k)
        out_tail[t + 1024 * k] = sv[k] * inv;
}

// ---------------------------------------------------------------------------
// Kernel 2: out[n,o] = b_q[n] * dot(patch[n,:], Wout[o,:])  (bf16 MFMA GEMM)
// grid(by=128, bx=8), block(256) = 4 waves, each wave computes 32x32 of 64x64
// ---------------------------------------------------------------------------
__global__ __launch_bounds__(256) void gemm_kernel(const float* __restrict__ A,
                                                   const float* __restrict__ W,
                                                   float* __restrict__ out) {
    __shared__ unsigned short As[BM][LDK];
    __shared__ unsigned short Bs[BN][LDK];

    const int by = blockIdx.x;   // 0..127 row tile   (x fastest => same-by blocks
    const int bx = blockIdx.y;   // 0..7   col tile    land on the same XCD, sharing A in L2)
    const int tid  = threadIdx.x;
    const int wave = tid >> 6;
    const int lane = tid & 63;
    const int wr = wave >> 1, wc = wave & 1;
    const int quad = lane >> 4, l16 = lane & 15;

    const float* bq = out + (size_t)NPTS * DDIM;   // written by bq_kernel

    // staging: thread t loads 16 contiguous fp32 of row sr at col seg sc
    const int sr = tid >> 2;          // 0..63
    const int sc = (tid & 3) << 4;    // 0,16,32,48

    const float* Ag = A + (size_t)(by * BM + sr) * DDIM + sc;
    const float* Wg = W + (size_t)(bx * BN + sr) * DDIM + sc;

    f32x4 acc[2][2] = {};

    for (int ks = 0; ks < DDIM / BK; ++ks) {
        const float* ap = Ag + ks * BK;
        const float* wp = Wg + ks * BK;
        float4 av0 = *(const float4*)(ap);
        float4 av1 = *(const float4*)(ap + 4);
        float4 av2 = *(const float4*)(ap + 8);
        float4 av3 = *(const float4*)(ap + 12);
        float4 wv0 = *(const float4*)(wp);
        float4 wv1 = *(const float4*)(wp + 4);
        float4 wv2 = *(const float4*)(wp + 8);
        float4 wv3 = *(const float4*)(wp + 12);

        __syncthreads();  // previous stage's compute done before overwrite

        us8 a01 = { f2bf(av0.x), f2bf(av0.y), f2bf(av0.z), f2bf(av0.w),
                    f2bf(av1.x), f2bf(av1.y), f2bf(av1.z), f2bf(av1.w) };
        us8 a23 = { f2bf(av2.x), f2bf(av2.y), f2bf(av2.z), f2bf(av2.w),
                    f2bf(av3.x), f2bf(av3.y), f2bf(av3.z), f2bf(av3.w) };
        us8 w01 = { f2bf(wv0.x), f2bf(wv0.y), f2bf(wv0.z), f2bf(wv0.w),
                    f2bf(wv1.x), f2bf(wv1.y), f2bf(wv1.z), f2bf(wv1.w) };
        us8 w23 = { f2bf(wv2.x), f2bf(wv2.y), f2bf(wv2.z), f2bf(wv2.w),
                    f2bf(wv3.x), f2bf(wv3.y), f2bf(wv3.z), f2bf(wv3.w) };
        *(us8*)&As[sr][sc]     = a01;
        *(us8*)&As[sr][sc + 8] = a23;
        *(us8*)&Bs[sr][sc]     = w01;
        *(us8*)&Bs[sr][sc + 8] = w23;

        __syncthreads();

#pragma unroll
        for (int kk = 0; kk < 2; ++kk) {
            const int kb = kk * 32 + quad * 8;
            bf16x8 a0 = *(const bf16x8*)&As[wr * 32 + l16][kb];
            bf16x8 a1 = *(const bf16x8*)&As[wr * 32 + 16 + l16][kb];
            bf16x8 b0 = *(const bf16x8*)&Bs[wc * 32 + l16][kb];
            bf16x8 b1 = *(const bf16x8*)&Bs[wc * 32 + 16 + l16][kb];
            acc[0][0] = __builtin_amdgcn_mfma_f32_16x16x32_bf16(a0, b0, acc[0][0], 0, 0, 0);
            acc[0][1] = __builtin_amdgcn_mfma_f32_16x16x32_bf16(a0, b1, acc[0][1], 0, 0, 0);
            acc[1][0] = __builtin_amdgcn_mfma_f32_16x16x32_bf16(a1, b0, acc[1][0], 0, 0, 0);
            acc[1][1] = __builtin_amdgcn_mfma_f32_16x16x32_bf16(a1, b1, acc[1][1], 0, 0, 0);
        }
    }

    // epilogue: C/D layout col=lane&15, row=quad*4+reg  [verified m89/m91]
#pragma unroll
    for (int i = 0; i < 2; ++i) {
        const int rbase = by * BM + wr * 32 + i * 16 + quad * 4;
#pragma unroll
        for (int rg = 0; rg < 4; ++rg) {
            const int grow = rbase + rg;
            const float scale = bq[grow];
#pragma unroll
            for (int j = 0; j < 2; ++j) {
                const int gcol = bx * BN + wc * 32 + j * 16 + l16;
                out[(size_t)grow * DDIM + gcol] = acc[i][j][rg] * scale;
            }
        }
    }
}

extern "C" void kernel_launch(void* const* d_in, const int* in_sizes, int n_in,
                              void* d_out, int out_size, void* d_ws, size_t ws_size,
                              hipStream_t stream) {
    const float* patch = (const float*)d_in[0];   // (8192, 512)
    const float* resid = (const float*)d_in[1];   // (8192,)
    // d_in[2] = Wq, d_in[3] = Wk : provably unused (softmax row-sums are 1)
    const float* wout  = (const float*)d_in[4];   // (512, 512)
    float* out = (float*)d_out;                   // attended (N*D) then b_q (N)

    bq_kernel<<<1, 1024, 0, stream>>>(resid, out + (size_t)NPTS * DDIM);
    gemm_kernel<<<dim3(NPTS / BM, DDIM / BN), 256, 0, stream>>>(patch, wout, out);
}

// Round 2
// 89.003 us; speedup vs baseline: 1.0406x; 1.0406x over previous
//
#include <hip/hip_runtime.h>
#include <hip/hip_bf16.h>

// N=8192, D=512. Algebraic reduction (verified R1, absmax 3.8e-6):
//   softmax row-sums are 1 => b_q = sigmoid(r)/(sum sigmoid(r) + N*1e-8)
//   attended = (patch * b_q[:,None]) @ Wout^T ;  Wq/Wk provably unused.
// Out layout: attended (N*D fp32) then b_q (N fp32).
//
// R2 structure: k1 = Wout->bf16 cvt (to d_ws) + b_q (1 extra block).
//               k2 = GEMM, A staged once via LDS (fused fp32->bf16),
//                    B frags read directly from L2-resident bf16 W
//                    (zero K-loop barriers), epilogue scales by b_q.

#define NPTS 8192
#define DDIM 512
#define BM   64            // rows per block
#define LDK  (DDIM + 8)    // 520: row stride 1040B = 65*16B (odd) -> conflict-free b128

typedef __attribute__((ext_vector_type(8))) short bf16x8;
typedef __attribute__((ext_vector_type(4))) float f32x4;
typedef __attribute__((ext_vector_type(8))) unsigned short us8;
typedef __attribute__((ext_vector_type(4))) unsigned short us4;

static __device__ __forceinline__ unsigned short f2bf(float f) {
    unsigned int u = __float_as_uint(f);
    u += 0x7fffu + ((u >> 16) & 1u);     // RNE fp32->bf16
    return (unsigned short)(u >> 16);
}

// ---------------------------------------------------------------------------
// Kernel 1: blocks 0..127 convert Wout (512x512 fp32) -> bf16 in ws.
//           block 128 computes b_q into out tail.
// ---------------------------------------------------------------------------
__global__ __launch_bounds__(256) void setup_kernel(const float* __restrict__ wout,
                                                    const float* __restrict__ r,
                                                    unsigned short* __restrict__ wbf,
                                                    float* __restrict__ bq) {
    const int t = threadIdx.x;
    if (blockIdx.x < 128) {
        const int f = blockIdx.x * 2048 + t * 8;
        float4 v0 = *(const float4*)(wout + f);
        float4 v1 = *(const float4*)(wout + f + 4);
        us8 o = { f2bf(v0.x), f2bf(v0.y), f2bf(v0.z), f2bf(v0.w),
                  f2bf(v1.x), f2bf(v1.y), f2bf(v1.z), f2bf(v1.w) };
        *(us8*)(wbf + f) = o;
    } else {
        // b_q: 256 threads x 32 elements
        float sv[32];
        float local = 0.0f;
#pragma unroll
        for (int k = 0; k < 32; ++k) {
            float x = r[t + 256 * k];
            float s = 1.0f / (1.0f + __expf(-x) * 1.0f);
            s = 1.0f / (1.0f + expf(-x));   // precise sigmoid
            sv[k] = s;
            local += s;
        }
#pragma unroll
        for (int off = 32; off >= 1; off >>= 1)
            local += __shfl_down(local, off, 64);
        __shared__ float wsum[4];
        __shared__ float stot;
        if ((t & 63) == 0) wsum[t >> 6] = local;
        __syncthreads();
        if (t == 0) stot = wsum[0] + wsum[1] + wsum[2] + wsum[3];
        __syncthreads();
        const float inv = 1.0f / (stot + (float)NPTS * 1e-8f);
#pragma unroll
        for (int k = 0; k < 32; ++k)
            bq[t + 256 * k] = sv[k] * inv;
    }
}

// ---------------------------------------------------------------------------
// Kernel 2: out[n,o] = b_q[n] * dot(patch[n,:], Wout[o,:])
// grid(128,2) blocks of 512 thr; block = 64 rows x 256 cols.
// Wave w: rows 0..63 of strip, cols [by*256 + w*32, +32) as 4x2 16x16 tiles.
// ---------------------------------------------------------------------------
__global__ __launch_bounds__(512) void gemm_kernel(const float* __restrict__ A,
                                                   const unsigned short* __restrict__ wbf,
                                                   float* __restrict__ out) {
    __shared__ unsigned short As[BM][LDK];

    const int rs   = blockIdx.x;            // 0..127 row strip (x-fastest: the 2
    const int half = blockIdx.y;            // blocks of a strip are ids rs, rs+128
    const int tid  = threadIdx.x;           // -> same XCD (128 % 8 == 0))
    const int wave = tid >> 6;
    const int lane = tid & 63;
    const int quad = lane >> 4, l16 = lane & 15;

    const float* bq = out + (size_t)NPTS * DDIM;   // from setup_kernel

    // ---- stage A strip (64x512 fp32 -> bf16 LDS), read once, coalesced ----
    const float* Ab = A + (size_t)rs * BM * DDIM;
#pragma unroll
    for (int i = 0; i < 16; ++i) {
        const int f = tid * 4 + i * 2048;          // 0..32767
        const int row = f >> 9, col = f & 511;
        float4 v = *(const float4*)(Ab + f);
        us4 o = { f2bf(v.x), f2bf(v.y), f2bf(v.z), f2bf(v.w) };
        *(us4*)&As[row][col] = o;
    }
    __syncthreads();   // the only barrier in this kernel

    // ---- K-loop: B frags straight from global (L2-resident 512KB bf16 W) ----
    const int c0 = half * 256 + wave * 32;
    // B operand layout (16x16x32): lane reads W[n = c0+j*16+l16][k = kc*32+quad*8 ..+8]
    const unsigned short* wb0 = wbf + (size_t)(c0 + l16) * DDIM + quad * 8;
    const unsigned short* wb1 = wb0 + 16 * DDIM;

    f32x4 acc[4][2] = {};

    bf16x8 bc0 = *(const bf16x8*)(wb0);
    bf16x8 bc1 = *(const bf16x8*)(wb1);

#pragma unroll
    for (int kc = 0; kc < 16; ++kc) {
        bf16x8 bn0, bn1;
        if (kc < 15) {
            bn0 = *(const bf16x8*)(wb0 + (kc + 1) * 32);
            bn1 = *(const bf16x8*)(wb1 + (kc + 1) * 32);
        }
        const int kb = kc * 32 + quad * 8;
        bf16x8 a0 = *(const bf16x8*)&As[l16][kb];
        bf16x8 a1 = *(const bf16x8*)&As[16 + l16][kb];
        bf16x8 a2 = *(const bf16x8*)&As[32 + l16][kb];
        bf16x8 a3 = *(const bf16x8*)&As[48 + l16][kb];
        acc[0][0] = __builtin_amdgcn_mfma_f32_16x16x32_bf16(a0, bc0, acc[0][0], 0, 0, 0);
        acc[1][0] = __builtin_amdgcn_mfma_f32_16x16x32_bf16(a1, bc0, acc[1][0], 0, 0, 0);
        acc[2][0] = __builtin_amdgcn_mfma_f32_16x16x32_bf16(a2, bc0, acc[2][0], 0, 0, 0);
        acc[3][0] = __builtin_amdgcn_mfma_f32_16x16x32_bf16(a3, bc0, acc[3][0], 0, 0, 0);
        acc[0][1] = __builtin_amdgcn_mfma_f32_16x16x32_bf16(a0, bc1, acc[0][1], 0, 0, 0);
        acc[1][1] = __builtin_amdgcn_mfma_f32_16x16x32_bf16(a1, bc1, acc[1][1], 0, 0, 0);
        acc[2][1] = __builtin_amdgcn_mfma_f32_16x16x32_bf16(a2, bc1, acc[2][1], 0, 0, 0);
        acc[3][1] = __builtin_amdgcn_mfma_f32_16x16x32_bf16(a3, bc1, acc[3][1], 0, 0, 0);
        bc0 = bn0;
        bc1 = bn1;
    }

    // ---- epilogue: C/D layout col=l16, row=quad*4+reg [m89/m91] ----
#pragma unroll
    for (int i = 0; i < 4; ++i) {
        const int rbase = rs * BM + i * 16 + quad * 4;
#pragma unroll
        for (int rg = 0; rg < 4; ++rg) {
            const int grow = rbase + rg;
            const float scale = bq[grow];
            out[(size_t)grow * DDIM + c0 + l16]      = acc[i][0][rg] * scale;
            out[(size_t)grow * DDIM + c0 + 16 + l16] = acc[i][1][rg] * scale;
        }
    }
}

extern "C" void kernel_launch(void* const* d_in, const int* in_sizes, int n_in,
                              void* d_out, int out_size, void* d_ws, size_t ws_size,
                              hipStream_t stream) {
    const float* patch = (const float*)d_in[0];   // (8192, 512)
    const float* resid = (const float*)d_in[1];   // (8192,)
    // d_in[2]=Wq, d_in[3]=Wk unused (softmax row-sums are exactly 1)
    const float* wout  = (const float*)d_in[4];   // (512, 512)
    float* out = (float*)d_out;
    unsigned short* wbf = (unsigned short*)d_ws;  // 512KB bf16 W

    setup_kernel<<<129, 256, 0, stream>>>(wout, resid, wbf, out + (size_t)NPTS * DDIM);
    gemm_kernel<<<dim3(128, 2), 512, 0, stream>>>(patch, wbf, out);
}